// Round 6
// baseline (659.975 us; speedup 1.0000x reference)
//
#include <hip/hip_runtime.h>
#include <stdint.h>

typedef __bf16 bf16x8 __attribute__((ext_vector_type(8)));
typedef float  floatx4 __attribute__((ext_vector_type(4)));
typedef int    i32x4  __attribute__((ext_vector_type(4)));

#define T_LEN 512
#define NG    (T_LEN / 4)   // 128 time-groups of 4 steps
#define BT    4             // batch rows per block -> 128 blocks
#define NTHR  1024          // 16 waves: 0-7 = layer0, 8-15 = layer1; loaders on all
#define XS    72            // x group-tile row stride (bf16)
#define HIS   144           // h int8 LDS row stride (bytes)
#define HFS   132           // final h1 fp32 row stride

#if __has_builtin(__builtin_amdgcn_exp2f)
#define EXP2(x) __builtin_amdgcn_exp2f(x)
#else
#define EXP2(x) exp2f(x)
#endif

#define MFMA_BF(a,b,c)  __builtin_amdgcn_mfma_f32_16x16x32_bf16((a),(b),(c),0,0,0)
#define MFMA_I8(a,b,c)  __builtin_amdgcn_mfma_i32_16x16x64_i8((a),(b),(c),0,0,0)

// Raw workgroup barrier: drains LDS ops only (lgkmcnt), NOT vmcnt.
#define BARRIER_LDS() asm volatile("s_waitcnt lgkmcnt(0)\n\ts_barrier" ::: "memory")

// quantization: h -> q*1/127 ; w -> q*1/254 (|w| clamped at 0.5)
#define L2E   1.4426950408889634f
#define S_RZ  (-L2E / (254.f * 127.f))        // i32 -> -log2e * preact
#define S_N   (-2.f * L2E / (254.f * 127.f))  // i32 -> -2*log2e * preact

__device__ __forceinline__ float rcpf(float x) { return __builtin_amdgcn_rcpf(x); }

__device__ __forceinline__ bf16x8 wfrag_bf(const float* W, int ldk, int row, int k0, float scale) {
    const float* p = W + (size_t)row * ldk + k0;
    bf16x8 r;
    #pragma unroll
    for (int j = 0; j < 8; ++j) r[j] = (__bf16)(p[j] * scale);
    return r;
}
__device__ __forceinline__ i32x4 wfrag_i8(const float* W, int ldk, int row, int k0) {
    const float* p = W + (size_t)row * ldk + k0;
    i32x4 r;
    #pragma unroll
    for (int d = 0; d < 4; ++d) {
        uint32_t dw = 0;
        #pragma unroll
        for (int j = 0; j < 4; ++j) {
            float q = __builtin_rintf(p[d * 4 + j] * 254.f);
            q = fminf(127.f, fmaxf(-127.f, q));
            dw |= ((uint32_t)((int)q & 0xff)) << (8 * j);
        }
        r[d] = (int)dw;
    }
    return r;
}

// SCHEDULE: group-side GEMMs run ONE GROUP AHEAD of consumption, spread
// 2 MFMAs per phase (p0: frag ds_read, p1/2/3: R/Z/N pairs), issued right
// after the barrier so they drain inside the hidden ds_read shadow.
// This also removes the group GEMM from the p=0 critical path entirely.
//   L0: x staged 2 groups ahead (same xg parity); accs pc* consumed in G,
//       pn* built during G for G+1; rollover at p=3.
//   L1: lag extended 4 -> 8 steps (s = tt-8); group GEMM during G on
//       h0g[(G-1)&1] feeds steps 4(G-2)+p consumed during G+1.
// setprio(1) wraps the MFMA cluster (T5); loaders spread across all 16 waves.
// All per-step math identical to the previous kernel -> bit-identical output.
__global__ __launch_bounds__(NTHR, 4) void gru_fused(
    const float* __restrict__ x,
    const float* __restrict__ Wih0, const float* __restrict__ Whh0,
    const float* __restrict__ bih0, const float* __restrict__ bhh0,
    const float* __restrict__ Wih1, const float* __restrict__ Whh1,
    const float* __restrict__ bih1, const float* __restrict__ bhh1,
    const float* __restrict__ Wfc,  const float* __restrict__ bfc,
    float* __restrict__ out)
{
    __shared__ __align__(16) __bf16      xg[2][16 * XS];    // x group tile (p+4b rows)
    __shared__ __align__(16) signed char h0b[2][16 * HIS];  // h0 b-major (L0 hidden)
    __shared__ __align__(16) signed char h0g[2][16 * HIS];  // h0 group tile (L1 input)
    __shared__ __align__(16) signed char h1b[2][16 * HIS];  // h1 b-major (L1 hidden)
    __shared__ __align__(16) float       hfin[16 * HFS];

    const int tid  = threadIdx.x;
    const int lane = tid & 63;
    const int ln16 = lane & 15;
    const int quad = lane >> 4;
    const int q8   = quad * 8;        // bf16 k-offset (elements)
    const int q16  = quad * 16;       // int8 k-offset (bytes)
    const int wave = tid >> 6;        // 0..15
    const int brow = blockIdx.x * BT;

    for (int i = tid; i < 16 * HIS; i += NTHR) {
        h0b[0][i] = 0; h0b[1][i] = 0;
        h0g[0][i] = 0; h0g[1][i] = 0;
        h1b[0][i] = 0; h1b[1][i] = 0;
    }
    for (int i = tid; i < 16 * XS; i += NTHR) {
        xg[0][i] = (__bf16)0.f; xg[1][i] = (__bf16)0.f;
    }
    __syncthreads();                  // init barrier

    // staging: 256 loaders = lanes 0..15 of ALL 16 waves (balanced skew)
    const bool loader = (lane < 16);
    const int lidx = wave * 16 + ln16;          // 0..255
    const int sb = (lidx >> 6) & 3, scg = lidx & 63;
    const float* xp = x + (size_t)(brow + sb) * T_LEN * 64 + scg;
    float vx0 = 0.f, vx1 = 0.f, vx2 = 0.f;
    if (loader) {
        // prologue: x(0..3)->xg[0], x(4..7)->xg[1]; preload x(8),x(9),x(10)
        #pragma unroll
        for (int t = 0; t < 8; ++t)
            xg[t >> 2][((t & 3) + 4 * sb) * XS + scg] = (__bf16)xp[(size_t)t * 64];
        vx0 = xp[8 * 64];
        vx1 = xp[9 * 64];
        vx2 = xp[10 * 64];
    }

    if (wave < 8) {
        // ===== layer-0: cols [16w,16w+16); x-side bf16 (group-ahead), hidden i8 =====
        const int c = wave * 16 + ln16;
        const float bNi = -2.f * L2E * bih0[256 + c];
        const float bNh = -2.f * L2E * bhh0[256 + c];
        const float bR  = -L2E * (bih0[c] + bhh0[c]);
        const float bZ  = -L2E * (bih0[128 + c] + bhh0[128 + c]);
        bf16x8 wI[3][2];
        i32x4  wH[3][2];
        #pragma unroll
        for (int g = 0; g < 3; ++g) {
            const int row = g * 128 + c;
            const float sc = (g == 2) ? (-2.f * L2E) : (-L2E);
            #pragma unroll
            for (int q = 0; q < 2; ++q) {
                wI[g][q] = wfrag_bf(Wih0, 64, row, q * 32 + q8, sc);
                wH[g][q] = wfrag_i8(Whh0, 128, row, q * 64 + q16);
            }
        }
        __syncthreads();              // publish xg[0], xg[1]

        float hfv = 0.f;
        floatx4 pcR, pcZ, pcN;        // current-group x-side accs (consumed now)
        floatx4 pnR, pnZ, pnN;        // next-group accs (built this group)
        bf16x8 gx0, gx1;              // next-group A-frags
        {   // prologue GEMM: group-0 accs from xg[0]
            bf16x8 ax0 = *(const bf16x8*)&xg[0][ln16 * XS + q8];
            bf16x8 ax1 = *(const bf16x8*)&xg[0][ln16 * XS + 32 + q8];
            floatx4 fR  = {bR, bR, bR, bR};
            floatx4 fZ  = {bZ, bZ, bZ, bZ};
            floatx4 fN  = {bNi, bNi, bNi, bNi};
            fR = MFMA_BF(ax0, wI[0][0], fR); fR = MFMA_BF(ax1, wI[0][1], fR);
            fZ = MFMA_BF(ax0, wI[1][0], fZ); fZ = MFMA_BF(ax1, wI[1][1], fZ);
            fN = MFMA_BF(ax0, wI[2][0], fN); fN = MFMA_BF(ax1, wI[2][1], fN);
            pcR = fR; pcZ = fZ; pcN = fN;
        }

        for (int G = 0; G <= NG + 1; ++G) {
            #pragma unroll
            for (int p = 0; p < 4; ++p) {
                const int tt = 4 * G + p;
                __builtin_amdgcn_sched_barrier(0);
                BARRIER_LDS();        // the ONLY per-step barrier (lgkm only)
                // staging: write x(tt+8) into xg[G&1]; load x(tt+11)
                if (loader) {
                    if (tt + 8 < T_LEN)
                        xg[G & 1][(p + 4 * sb) * XS + scg] = (__bf16)vx0;
                    vx0 = vx1; vx1 = vx2;
                    int tl = tt + 11; if (tl > T_LEN - 1) tl = T_LEN - 1;
                    vx2 = xp[(size_t)tl * 64];
                }

                if (G < NG) {         // active L0 step tt
                    const int Rp = (tt + 1) & 1, Wc = tt & 1;
                    i32x4 ah[2];      // hidden ds_read (issue first)
                    #pragma unroll
                    for (int q = 0; q < 2; ++q)
                        ah[q] = *(const i32x4*)&h0b[Rp][ln16 * HIS + q * 64 + q16];
                    if (p == 0 && G < NG - 1) {   // next-group A-frags
                        gx0 = *(const bf16x8*)&xg[(G + 1) & 1][ln16 * XS + q8];
                        gx1 = *(const bf16x8*)&xg[(G + 1) & 1][ln16 * XS + 32 + q8];
                    }
                    __builtin_amdgcn_s_setprio(1);
                    if (G < NG - 1) { // group-ahead MFMAs fill the read shadow
                        if (p == 1) {
                            floatx4 f = {bR, bR, bR, bR};
                            f = MFMA_BF(gx0, wI[0][0], f); f = MFMA_BF(gx1, wI[0][1], f);
                            pnR = f;
                        }
                        if (p == 2) {
                            floatx4 f = {bZ, bZ, bZ, bZ};
                            f = MFMA_BF(gx0, wI[1][0], f); f = MFMA_BF(gx1, wI[1][1], f);
                            pnZ = f;
                        }
                        if (p == 3) {
                            floatx4 f = {bNi, bNi, bNi, bNi};
                            f = MFMA_BF(gx0, wI[2][0], f); f = MFMA_BF(gx1, wI[2][1], f);
                            pnN = f;
                        }
                    }
                    i32x4 cR = {0,0,0,0}, cZ = {0,0,0,0}, cNh = {0,0,0,0};
                    #pragma unroll
                    for (int q = 0; q < 2; ++q) {
                        cR  = MFMA_I8(ah[q], wH[0][q], cR);
                        cZ  = MFMA_I8(ah[q], wH[1][q], cZ);
                        cNh = MFMA_I8(ah[q], wH[2][q], cNh);
                    }
                    __builtin_amdgcn_s_setprio(0);
                    // gate math; x-side value for this step = pc acc reg p
                    const float pr  = fmaf((float)cR[0],  S_RZ, pcR[p]);
                    const float pz  = fmaf((float)cZ[0],  S_RZ, pcZ[p]);
                    const float phn = fmaf((float)cNh[0], S_N,  bNh);
                    const float r = rcpf(1.f + EXP2(pr));
                    const float z = rcpf(1.f + EXP2(pz));
                    const float n = 2.f * rcpf(1.f + EXP2(fmaf(r, phn, pcN[p]))) - 1.f;
                    const float h = n + z * (hfv - n);
                    hfv = h;
                    const signed char qv = (signed char)(int)__builtin_rintf(h * 127.f);
                    h0b[Wc][(quad * 4) * HIS + c] = qv;          // for L0 hidden (t+1)
                    h0g[G & 1][(p + 4 * quad) * HIS + c] = qv;   // group tile for L1
                    if (p == 3 && G < NG - 1) {                  // group rollover
                        pcR = pnR; pcZ = pnZ; pcN = pnN;
                    }
                }
            }
        }
    } else {
        // ===== layer-1 (lag 8): cols [16wv,16wv+16); all int8, group-ahead =====
        const int wv = wave - 8;
        const int c  = wv * 16 + ln16;
        const float bNi1 = -2.f * L2E * bih1[256 + c];
        const float bNh1 = -2.f * L2E * bhh1[256 + c];
        const float bR1  = -L2E * (bih1[c] + bhh1[c]);
        const float bZ1  = -L2E * (bih1[128 + c] + bhh1[128 + c]);
        i32x4 wI[3][2], wH[3][2];
        #pragma unroll
        for (int g = 0; g < 3; ++g) {
            const int row = g * 128 + c;
            #pragma unroll
            for (int q = 0; q < 2; ++q) {
                wI[g][q] = wfrag_i8(Wih1, 128, row, q * 64 + q16);
                wH[g][q] = wfrag_i8(Whh1, 128, row, q * 64 + q16);
            }
        }
        __syncthreads();              // match L0's xg-publish barrier

        float hfv = 0.f;
        i32x4 qcR = {0,0,0,0}, qcZ = {0,0,0,0}, qcN = {0,0,0,0};  // consumed now
        i32x4 qnR, qnZ, qnN;          // built this group for next
        i32x4 ga[2];                  // group A-frags (h0 group tile)
        for (int G = 0; G <= NG + 1; ++G) {
            #pragma unroll
            for (int p = 0; p < 4; ++p) {
                const int tt = 4 * G + p;
                __builtin_amdgcn_sched_barrier(0);
                BARRIER_LDS();
                if (loader) {
                    if (tt + 8 < T_LEN)
                        xg[G & 1][(p + 4 * sb) * XS + scg] = (__bf16)vx0;
                    vx0 = vx1; vx1 = vx2;
                    int tl = tt + 11; if (tl > T_LEN - 1) tl = T_LEN - 1;
                    vx2 = xp[(size_t)tl * 64];
                }

                const int s = tt - 8;             // L1 step this interval
                const bool grp = (G >= 1 && G <= NG);
                if (p == 0 && grp) {              // group A-frags: h0 of group G-1
                    ga[0] = *(const i32x4*)&h0g[(G - 1) & 1][ln16 * HIS + q16];
                    ga[1] = *(const i32x4*)&h0g[(G - 1) & 1][ln16 * HIS + 64 + q16];
                }
                i32x4 a1[2];
                if (s >= 0) {                     // hidden ds_read (issue first)
                    const int Rp = (s + 1) & 1;
                    #pragma unroll
                    for (int q = 0; q < 2; ++q)
                        a1[q] = *(const i32x4*)&h1b[Rp][ln16 * HIS + q * 64 + q16];
                }
                __builtin_amdgcn_s_setprio(1);
                if (grp) {                        // group-ahead MFMAs in read shadow
                    if (p == 1) {
                        i32x4 a = {0,0,0,0};
                        a = MFMA_I8(ga[0], wI[0][0], a); a = MFMA_I8(ga[1], wI[0][1], a);
                        qnR = a;
                    }
                    if (p == 2) {
                        i32x4 a = {0,0,0,0};
                        a = MFMA_I8(ga[0], wI[1][0], a); a = MFMA_I8(ga[1], wI[1][1], a);
                        qnZ = a;
                    }
                    if (p == 3) {
                        i32x4 a = {0,0,0,0};
                        a = MFMA_I8(ga[0], wI[2][0], a); a = MFMA_I8(ga[1], wI[2][1], a);
                        qnN = a;
                    }
                }
                if (s >= 0) {
                    i32x4 cR = {0,0,0,0}, cZ = {0,0,0,0}, cNh = {0,0,0,0};
                    #pragma unroll
                    for (int q = 0; q < 2; ++q) {
                        cR  = MFMA_I8(a1[q], wH[0][q], cR);
                        cZ  = MFMA_I8(a1[q], wH[1][q], cZ);
                        cNh = MFMA_I8(a1[q], wH[2][q], cNh);
                    }
                    __builtin_amdgcn_s_setprio(0);
                    // gate math; input-side value = qc acc reg p (exact i32 add)
                    const float pr  = fmaf((float)(cR[0] + qcR[p]), S_RZ, bR1);
                    const float pz  = fmaf((float)(cZ[0] + qcZ[p]), S_RZ, bZ1);
                    const float pin = fmaf((float)qcN[p], S_N, bNi1);
                    const float phn = fmaf((float)cNh[0], S_N, bNh1);
                    const float r = rcpf(1.f + EXP2(pr));
                    const float z = rcpf(1.f + EXP2(pz));
                    const float n = 2.f * rcpf(1.f + EXP2(fmaf(r, phn, pin))) - 1.f;
                    const float h = n + z * (hfv - n);
                    hfv = h;
                    h1b[s & 1][(quad * 4) * HIS + c] =
                        (signed char)(int)__builtin_rintf(h * 127.f);
                } else {
                    __builtin_amdgcn_s_setprio(0);
                }
                if (p == 3 && grp) {              // group rollover
                    qcR = qnR; qcZ = qnZ; qcN = qnN;
                }
            }
        }
        // publish final h1 (fp32 state) for the FC epilogue
        hfin[(quad * 4) * HFS + c] = hfv;
    }

    __syncthreads();
    // final FC: out[b] = h1(T-1)[b,:] . Wfc + bfc  (tile rows 0,4,8,12)
    {
        const int row = tid >> 5, l = tid & 31;
        if (row < 16 && (row & 3) == 0) {
            float s = 0.f;
            #pragma unroll
            for (int k = 0; k < 4; ++k)
                s += hfin[row * HFS + l + 32 * k] * Wfc[l + 32 * k];
            #pragma unroll
            for (int d = 16; d >= 1; d >>= 1) s += __shfl_down(s, d, 32);
            if (l == 0) out[brow + (row >> 2)] = s + bfc[0];
        }
    }
}

extern "C" void kernel_launch(void* const* d_in, const int* in_sizes, int n_in,
                              void* d_out, int out_size, void* d_ws, size_t ws_size,
                              hipStream_t stream) {
    const float* x    = (const float*)d_in[0];
    const float* Wih0 = (const float*)d_in[1];
    const float* Whh0 = (const float*)d_in[2];
    const float* bih0 = (const float*)d_in[3];
    const float* bhh0 = (const float*)d_in[4];
    const float* Wih1 = (const float*)d_in[5];
    const float* Whh1 = (const float*)d_in[6];
    const float* bih1 = (const float*)d_in[7];
    const float* bhh1 = (const float*)d_in[8];
    const float* Wfc  = (const float*)d_in[9];
    const float* bfc  = (const float*)d_in[10];
    float* out = (float*)d_out;

    hipLaunchKernelGGL(gru_fused, dim3(512 / BT), dim3(NTHR), 0, stream,
                       x, Wih0, Whh0, bih0, bhh0, Wih1, Whh1, bih1, bhh1, Wfc, bfc, out);
}

// Round 7
// 562.831 us; speedup vs baseline: 1.1726x; 1.1726x over previous
//
#include <hip/hip_runtime.h>
#include <stdint.h>

typedef __bf16 bf16x8 __attribute__((ext_vector_type(8)));
typedef float  floatx4 __attribute__((ext_vector_type(4)));
typedef int    i32x4  __attribute__((ext_vector_type(4)));

#define T_LEN 512
#define NG    (T_LEN / 4)   // 128 time-groups of 4 steps
#define NGK   (NG + 1)      // G = 0..NGK inclusive -> k = 4G+p in 0..T+7
#define BT    4             // batch rows per block -> 128 blocks
#define NTHR  1024          // 16 waves: 0-7 = layer0, 8-15 = layer1; loaders on all
#define XS    72            // x group-tile row stride (bf16)
#define HIS   144           // h int8 LDS row stride (bytes)
#define HFS   132           // final h1 fp32 row stride

#if __has_builtin(__builtin_amdgcn_exp2f)
#define EXP2(x) __builtin_amdgcn_exp2f(x)
#else
#define EXP2(x) exp2f(x)
#endif

#define MFMA_BF(a,b,c)  __builtin_amdgcn_mfma_f32_16x16x32_bf16((a),(b),(c),0,0,0)
#define MFMA_I8(a,b,c)  __builtin_amdgcn_mfma_i32_16x16x64_i8((a),(b),(c),0,0,0)

// Raw workgroup barrier: drains LDS ops only (lgkmcnt), NOT vmcnt.
#define BARRIER_LDS() asm volatile("s_waitcnt lgkmcnt(0)\n\ts_barrier" ::: "memory")

// quantization: h -> q*1/127 ; w -> q*1/254 (|w| clamped at 0.5)
#define L2E   1.4426950408889634f
#define S_RZ  (-L2E / (254.f * 127.f))        // i32 -> -log2e * preact
#define S_N   (-2.f * L2E / (254.f * 127.f))  // i32 -> -2*log2e * preact

__device__ __forceinline__ float rcpf(float x) { return __builtin_amdgcn_rcpf(x); }

__device__ __forceinline__ bf16x8 wfrag_bf(const float* W, int ldk, int row, int k0, float scale) {
    const float* p = W + (size_t)row * ldk + k0;
    bf16x8 r;
    #pragma unroll
    for (int j = 0; j < 8; ++j) r[j] = (__bf16)(p[j] * scale);
    return r;
}
__device__ __forceinline__ i32x4 wfrag_i8(const float* W, int ldk, int row, int k0) {
    const float* p = W + (size_t)row * ldk + k0;
    i32x4 r;
    #pragma unroll
    for (int d = 0; d < 4; ++d) {
        uint32_t dw = 0;
        #pragma unroll
        for (int j = 0; j < 4; ++j) {
            float q = __builtin_rintf(p[d * 4 + j] * 254.f);
            q = fminf(127.f, fmaxf(-127.f, q));
            dw |= ((uint32_t)((int)q & 0xff)) << (8 * j);
        }
        r[d] = (int)dw;
    }
    return r;
}

// SCHEDULE (this round): one-phase-lag group GEMMs, phase-staggered per layer.
// Flat interval counter k = 4G+p; ONE lgkm-only barrier per interval.
//   L0 (step t = k-1): group GEMM at p==0 on xg[G&1] (steps 4G..4G+3) into pn;
//     rollover pc<-pn at END of p0 (after the gate consumed old pc[3]); the
//     gate at interval k uses pc[(p+3)&3] computed LAST group-phase -> the
//     group GEMM is OFF the gate critical path in every phase.
//   L1 (step s = k-7): group GEMM at p==2 on h0g[(G-1)&1] (L0 group G-1,
//     complete since k=4G-4+4=4G); qc rollover at end of p2; gate uses
//     qc[(p+1)&3]. Staggering L0@p0 / L1@p2 flattens per-SIMD MFMA issue
//     (peak 48 -> 36 per interval).
// Register hygiene (round-6 spill lesson): A-frags and pn/qn are PHASE-LOCAL;
// cross-barrier live state = pc/qc only (identical to the round-4 kernel).
// All acc indices are literals in the unrolled p-body. Math identical ->
// bit-identical output.
__global__ __launch_bounds__(NTHR, 4) void gru_fused(
    const float* __restrict__ x,
    const float* __restrict__ Wih0, const float* __restrict__ Whh0,
    const float* __restrict__ bih0, const float* __restrict__ bhh0,
    const float* __restrict__ Wih1, const float* __restrict__ Whh1,
    const float* __restrict__ bih1, const float* __restrict__ bhh1,
    const float* __restrict__ Wfc,  const float* __restrict__ bfc,
    float* __restrict__ out)
{
    __shared__ __align__(16) __bf16      xg[2][16 * XS];    // x group tile (p+4b rows)
    __shared__ __align__(16) signed char h0b[2][16 * HIS];  // h0 b-major (L0 hidden)
    __shared__ __align__(16) signed char h0g[2][16 * HIS];  // h0 group tile (L1 input)
    __shared__ __align__(16) signed char h1b[2][16 * HIS];  // h1 b-major (L1 hidden)
    __shared__ __align__(16) float       hfin[16 * HFS];

    const int tid  = threadIdx.x;
    const int lane = tid & 63;
    const int ln16 = lane & 15;
    const int quad = lane >> 4;
    const int q8   = quad * 8;        // bf16 k-offset (elements)
    const int q16  = quad * 16;       // int8 k-offset (bytes)
    const int wave = tid >> 6;        // 0..15
    const int brow = blockIdx.x * BT;

    for (int i = tid; i < 16 * HIS; i += NTHR) {
        h0b[0][i] = 0; h0b[1][i] = 0;
        h0g[0][i] = 0; h0g[1][i] = 0;
        h1b[0][i] = 0; h1b[1][i] = 0;
    }
    for (int i = tid; i < 16 * XS; i += NTHR) {
        xg[0][i] = (__bf16)0.f; xg[1][i] = (__bf16)0.f;
    }
    __syncthreads();                  // init barrier

    // staging: 256 loaders = lanes 0..15 of ALL 16 waves
    const bool loader = (lane < 16);
    const int lidx = wave * 16 + ln16;          // 0..255
    const int sb = (lidx >> 6) & 3, scg = lidx & 63;
    const float* xp = x + (size_t)(brow + sb) * T_LEN * 64 + scg;
    float vx0 = 0.f, vx1 = 0.f, vx2 = 0.f;
    if (loader) {
        // prologue: x(0..3) -> xg[0]; preload x(4),x(5),x(6)
        #pragma unroll
        for (int t = 0; t < 4; ++t)
            xg[0][(t + 4 * sb) * XS + scg] = (__bf16)xp[(size_t)t * 64];
        vx0 = xp[4 * 64];
        vx1 = xp[5 * 64];
        vx2 = xp[6 * 64];
    }
    // first read of xg[0] is after the k=0 BARRIER_LDS -> ordered.

    if (wave < 8) {
        // ===== layer-0: cols [16w,16w+16); x-side bf16 (lagged group), hidden i8 =====
        const int c = wave * 16 + ln16;
        const float bNi = -2.f * L2E * bih0[256 + c];
        const float bNh = -2.f * L2E * bhh0[256 + c];
        const float bR  = -L2E * (bih0[c] + bhh0[c]);
        const float bZ  = -L2E * (bih0[128 + c] + bhh0[128 + c]);
        bf16x8 wI[3][2];
        i32x4  wH[3][2];
        #pragma unroll
        for (int g = 0; g < 3; ++g) {
            const int row = g * 128 + c;
            const float sc = (g == 2) ? (-2.f * L2E) : (-L2E);
            #pragma unroll
            for (int q = 0; q < 2; ++q) {
                wI[g][q] = wfrag_bf(Wih0, 64, row, q * 32 + q8, sc);
                wH[g][q] = wfrag_i8(Whh0, 128, row, q * 64 + q16);
            }
        }

        float hfv = 0.f;
        floatx4 pcR = {0.f,0.f,0.f,0.f}, pcZ = {0.f,0.f,0.f,0.f}, pcN = {0.f,0.f,0.f,0.f};

        for (int G = 0; G <= NGK; ++G) {
            #pragma unroll
            for (int p = 0; p < 4; ++p) {
                const int k = 4 * G + p;
                __builtin_amdgcn_sched_barrier(0);
                BARRIER_LDS();        // the ONLY per-interval barrier (lgkm only)
                // staging: write x(k+4) into xg[(G+1)&1] row p+4sb; load x(k+7)
                if (loader) {
                    if (k + 4 < T_LEN)
                        xg[(G + 1) & 1][(p + 4 * sb) * XS + scg] = (__bf16)vx0;
                    vx0 = vx1; vx1 = vx2;
                    int tl = k + 7; if (tl > T_LEN - 1) tl = T_LEN - 1;
                    vx2 = xp[(size_t)tl * 64];
                }

                floatx4 pnR, pnZ, pnN;          // phase-local
                const bool doGrp = (p == 0) && (G < NG);
                if (doGrp) {                    // group GEMM: steps 4G..4G+3
                    bf16x8 gx0 = *(const bf16x8*)&xg[G & 1][ln16 * XS + q8];
                    bf16x8 gx1 = *(const bf16x8*)&xg[G & 1][ln16 * XS + 32 + q8];
                    floatx4 fR  = {bR, bR, bR, bR};
                    floatx4 fZ  = {bZ, bZ, bZ, bZ};
                    floatx4 fN  = {bNi, bNi, bNi, bNi};
                    fR = MFMA_BF(gx0, wI[0][0], fR); fR = MFMA_BF(gx1, wI[0][1], fR);
                    fZ = MFMA_BF(gx0, wI[1][0], fZ); fZ = MFMA_BF(gx1, wI[1][1], fZ);
                    fN = MFMA_BF(gx0, wI[2][0], fN); fN = MFMA_BF(gx1, wI[2][1], fN);
                    pnR = fR; pnZ = fZ; pnN = fN;
                }

                const int t = k - 1;            // L0 step this interval (lag 1)
                if (t >= 0 && t < T_LEN) {
                    i32x4 ah[2];                // hidden ds_read; parity p&1 (static)
                    #pragma unroll
                    for (int q = 0; q < 2; ++q)
                        ah[q] = *(const i32x4*)&h0b[p & 1][ln16 * HIS + q * 64 + q16];
                    i32x4 cR = {0,0,0,0}, cZ = {0,0,0,0}, cNh = {0,0,0,0};
                    #pragma unroll
                    for (int q = 0; q < 2; ++q) {
                        cR  = MFMA_I8(ah[q], wH[0][q], cR);
                        cZ  = MFMA_I8(ah[q], wH[1][q], cZ);
                        cNh = MFMA_I8(ah[q], wH[2][q], cNh);
                    }
                    // gate math; x-side acc index (p+3)&3 is a literal per phase
                    const float pr  = fmaf((float)cR[0],  S_RZ, pcR[(p + 3) & 3]);
                    const float pz  = fmaf((float)cZ[0],  S_RZ, pcZ[(p + 3) & 3]);
                    const float phn = fmaf((float)cNh[0], S_N,  bNh);
                    const float r = rcpf(1.f + EXP2(pr));
                    const float z = rcpf(1.f + EXP2(pz));
                    const float n = 2.f * rcpf(1.f + EXP2(fmaf(r, phn, pcN[(p + 3) & 3]))) - 1.f;
                    const float h = n + z * (hfv - n);
                    hfv = h;
                    const signed char qv = (signed char)(int)__builtin_rintf(h * 127.f);
                    h0b[(p + 1) & 1][(quad * 4) * HIS + c] = qv;           // for t+1
                    h0g[((unsigned)t >> 2) & 1][(((p + 3) & 3) + 4 * quad) * HIS + c] = qv;
                }
                if (doGrp) {                    // rollover AFTER gate consumed pc[3]
                    pcR = pnR; pcZ = pnZ; pcN = pnN;
                }
            }
        }
    } else {
        // ===== layer-1 (lag 7): cols [16wv,16wv+16); all int8, group @ p==2 =====
        const int wv = wave - 8;
        const int c  = wv * 16 + ln16;
        const float bNi1 = -2.f * L2E * bih1[256 + c];
        const float bNh1 = -2.f * L2E * bhh1[256 + c];
        const float bR1  = -L2E * (bih1[c] + bhh1[c]);
        const float bZ1  = -L2E * (bih1[128 + c] + bhh1[128 + c]);
        i32x4 wI[3][2], wH[3][2];
        #pragma unroll
        for (int g = 0; g < 3; ++g) {
            const int row = g * 128 + c;
            #pragma unroll
            for (int q = 0; q < 2; ++q) {
                wI[g][q] = wfrag_i8(Wih1, 128, row, q * 64 + q16);
                wH[g][q] = wfrag_i8(Whh1, 128, row, q * 64 + q16);
            }
        }

        float hfv = 0.f;
        i32x4 qcR = {0,0,0,0}, qcZ = {0,0,0,0}, qcN = {0,0,0,0};

        for (int G = 0; G <= NGK; ++G) {
            #pragma unroll
            for (int p = 0; p < 4; ++p) {
                const int k = 4 * G + p;
                __builtin_amdgcn_sched_barrier(0);
                BARRIER_LDS();
                if (loader) {
                    if (k + 4 < T_LEN)
                        xg[(G + 1) & 1][(p + 4 * sb) * XS + scg] = (__bf16)vx0;
                    vx0 = vx1; vx1 = vx2;
                    int tl = k + 7; if (tl > T_LEN - 1) tl = T_LEN - 1;
                    vx2 = xp[(size_t)tl * 64];
                }

                i32x4 qnR, qnZ, qnN;            // phase-local
                const bool doGrp = (p == 2) && (G >= 1) && (G <= NG);
                if (doGrp) {                    // group GEMM on h0 group G-1
                    const int g = G - 1;
                    i32x4 ga0 = *(const i32x4*)&h0g[g & 1][ln16 * HIS + q16];
                    i32x4 ga1 = *(const i32x4*)&h0g[g & 1][ln16 * HIS + 64 + q16];
                    i32x4 aR = {0,0,0,0}, aZ = {0,0,0,0}, aN = {0,0,0,0};
                    aR = MFMA_I8(ga0, wI[0][0], aR); aR = MFMA_I8(ga1, wI[0][1], aR);
                    aZ = MFMA_I8(ga0, wI[1][0], aZ); aZ = MFMA_I8(ga1, wI[1][1], aZ);
                    aN = MFMA_I8(ga0, wI[2][0], aN); aN = MFMA_I8(ga1, wI[2][1], aN);
                    qnR = aR; qnZ = aZ; qnN = aN;
                }

                const int s = k - 7;            // L1 step this interval (lag 7)
                if (s >= 0 && s < T_LEN) {
                    i32x4 a1[2];                // hidden ds_read; parity p&1 (static)
                    #pragma unroll
                    for (int q = 0; q < 2; ++q)
                        a1[q] = *(const i32x4*)&h1b[p & 1][ln16 * HIS + q * 64 + q16];
                    i32x4 cR = {0,0,0,0}, cZ = {0,0,0,0}, cNh = {0,0,0,0};
                    #pragma unroll
                    for (int q = 0; q < 2; ++q) {
                        cR  = MFMA_I8(a1[q], wH[0][q], cR);
                        cZ  = MFMA_I8(a1[q], wH[1][q], cZ);
                        cNh = MFMA_I8(a1[q], wH[2][q], cNh);
                    }
                    // gate math; input-side acc index (p+1)&3 is a literal per phase
                    const float pr  = fmaf((float)(cR[0] + qcR[(p + 1) & 3]), S_RZ, bR1);
                    const float pz  = fmaf((float)(cZ[0] + qcZ[(p + 1) & 3]), S_RZ, bZ1);
                    const float pin = fmaf((float)qcN[(p + 1) & 3], S_N, bNi1);
                    const float phn = fmaf((float)cNh[0], S_N, bNh1);
                    const float r = rcpf(1.f + EXP2(pr));
                    const float z = rcpf(1.f + EXP2(pz));
                    const float n = 2.f * rcpf(1.f + EXP2(fmaf(r, phn, pin))) - 1.f;
                    const float h = n + z * (hfv - n);
                    hfv = h;
                    h1b[(p + 1) & 1][(quad * 4) * HIS + c] =
                        (signed char)(int)__builtin_rintf(h * 127.f);
                }
                if (doGrp) {                    // rollover AFTER gate consumed qc[3]
                    qcR = qnR; qcZ = qnZ; qcN = qnN;
                }
            }
        }
        // publish final h1 (fp32 state) for the FC epilogue
        hfin[(quad * 4) * HFS + c] = hfv;
    }

    __syncthreads();
    // final FC: out[b] = h1(T-1)[b,:] . Wfc + bfc  (tile rows 0,4,8,12)
    {
        const int row = tid >> 5, l = tid & 31;
        if (row < 16 && (row & 3) == 0) {
            float s = 0.f;
            #pragma unroll
            for (int k = 0; k < 4; ++k)
                s += hfin[row * HFS + l + 32 * k] * Wfc[l + 32 * k];
            #pragma unroll
            for (int d = 16; d >= 1; d >>= 1) s += __shfl_down(s, d, 32);
            if (l == 0) out[brow + (row >> 2)] = s + bfc[0];
        }
    }
}

extern "C" void kernel_launch(void* const* d_in, const int* in_sizes, int n_in,
                              void* d_out, int out_size, void* d_ws, size_t ws_size,
                              hipStream_t stream) {
    const float* x    = (const float*)d_in[0];
    const float* Wih0 = (const float*)d_in[1];
    const float* Whh0 = (const float*)d_in[2];
    const float* bih0 = (const float*)d_in[3];
    const float* bhh0 = (const float*)d_in[4];
    const float* Wih1 = (const float*)d_in[5];
    const float* Whh1 = (const float*)d_in[6];
    const float* bih1 = (const float*)d_in[7];
    const float* bhh1 = (const float*)d_in[8];
    const float* Wfc  = (const float*)d_in[9];
    const float* bfc  = (const float*)d_in[10];
    float* out = (float*)d_out;

    hipLaunchKernelGGL(gru_fused, dim3(512 / BT), dim3(NTHR), 0, stream,
                       x, Wih0, Whh0, bih0, bhh0, Wih1, Whh1, bih1, bhh1, Wfc, bfc, out);
}

// Round 9
// 348.469 us; speedup vs baseline: 1.8939x; 1.6152x over previous
//
#include <hip/hip_runtime.h>
#include <stdint.h>

typedef __bf16 bf16x8 __attribute__((ext_vector_type(8)));
typedef float  floatx4 __attribute__((ext_vector_type(4)));
typedef int    i32x4  __attribute__((ext_vector_type(4)));

#define T_LEN 512
#define NG    (T_LEN / 4)   // 128 time-groups of 4 steps
#define BT    4             // batch rows per block -> 128 blocks
#define NTHR  1024          // 16 waves: 0-7 = layer0 (+x staging), 8-15 = layer1
#define XS    72            // x group-tile row stride (bf16)
#define HIS   144           // h int8 LDS row stride (bytes)
#define HFS   132           // final h1 fp32 row stride

#if __has_builtin(__builtin_amdgcn_exp2f)
#define EXP2(x) __builtin_amdgcn_exp2f(x)
#else
#define EXP2(x) exp2f(x)
#endif

#define MFMA_BF(a,b,c)  __builtin_amdgcn_mfma_f32_16x16x32_bf16((a),(b),(c),0,0,0)
#define MFMA_I8(a,b,c)  __builtin_amdgcn_mfma_i32_16x16x64_i8((a),(b),(c),0,0,0)

// Raw workgroup barrier: drains LDS ops only (lgkmcnt), NOT vmcnt — global
// x-prefetch loads stay in flight across barriers.
#define BARRIER_LDS() asm volatile("s_waitcnt lgkmcnt(0)\n\ts_barrier" ::: "memory")

// quantization: h -> q*1/127 ; w -> q*1/254 (|w| clamped at 0.5)
#define L2E   1.4426950408889634f
#define S_RZ  (-L2E / (254.f * 127.f))        // i32 -> -log2e * preact
#define S_N   (-2.f * L2E / (254.f * 127.f))  // i32 -> -2*log2e * preact

__device__ __forceinline__ float rcpf(float x) { return __builtin_amdgcn_rcpf(x); }

__device__ __forceinline__ bf16x8 wfrag_bf(const float* W, int ldk, int row, int k0, float scale) {
    const float* p = W + (size_t)row * ldk + k0;
    bf16x8 r;
    #pragma unroll
    for (int j = 0; j < 8; ++j) r[j] = (__bf16)(p[j] * scale);
    return r;
}
__device__ __forceinline__ i32x4 wfrag_i8(const float* W, int ldk, int row, int k0) {
    const float* p = W + (size_t)row * ldk + k0;
    i32x4 r;
    #pragma unroll
    for (int d = 0; d < 4; ++d) {
        uint32_t dw = 0;
        #pragma unroll
        for (int j = 0; j < 4; ++j) {
            float q = __builtin_rintf(p[d * 4 + j] * 254.f);
            q = fminf(127.f, fmaxf(-127.f, q));
            dw |= ((uint32_t)((int)q & 0xff)) << (8 * j);
        }
        r[d] = (int)dw;
    }
    return r;
}

// ROUND 9 = resubmit of round 8 (infra flake, no measurement): exact round-3
// structure (best measured: 271.5 us rocprof) + ONE change: s_setprio(1/0)
// around the MFMA clusters (T5). Rounds 6/7 proved every schedule
// restructuring (group-ahead, one-phase-lag, loader redistribution)
// regresses badly; this structure is the local optimum.
//   Feed-forward GEMMs time-batched: 16-row A-tile = 4 timesteps x 4 batch
//   rows (row = p + 4*b); one 6-MFMA set serves 4 steps. Hidden GEMMs
//   sequential, b-major rows {0,4,8,12}. L1 at group lag 4. ONE lgkm-only
//   barrier per step. Loaders = lanes 0..31 of L0 waves only.
// All math identical -> bit-identical output (absmax 0.01806641).
__global__ __launch_bounds__(NTHR, 4) void gru_fused(
    const float* __restrict__ x,
    const float* __restrict__ Wih0, const float* __restrict__ Whh0,
    const float* __restrict__ bih0, const float* __restrict__ bhh0,
    const float* __restrict__ Wih1, const float* __restrict__ Whh1,
    const float* __restrict__ bih1, const float* __restrict__ bhh1,
    const float* __restrict__ Wfc,  const float* __restrict__ bfc,
    float* __restrict__ out)
{
    __shared__ __align__(16) __bf16      xg[2][16 * XS];    // x group tile (p+4b rows)
    __shared__ __align__(16) signed char h0b[2][16 * HIS];  // h0 b-major (L0 hidden)
    __shared__ __align__(16) signed char h0g[2][16 * HIS];  // h0 group tile (L1 input)
    __shared__ __align__(16) signed char h1b[2][16 * HIS];  // h1 b-major (L1 hidden)
    __shared__ __align__(16) float       hfin[16 * HFS];

    const int tid  = threadIdx.x;
    const int lane = tid & 63;
    const int ln16 = lane & 15;
    const int quad = lane >> 4;
    const int q8   = quad * 8;        // bf16 k-offset (elements)
    const int q16  = quad * 16;       // int8 k-offset (bytes)
    const int wave = tid >> 6;        // 0..15
    const int brow = blockIdx.x * BT;

    for (int i = tid; i < 16 * HIS; i += NTHR) {
        h0b[0][i] = 0; h0b[1][i] = 0;
        h0g[0][i] = 0; h0g[1][i] = 0;
        h1b[0][i] = 0; h1b[1][i] = 0;
    }
    for (int i = tid; i < 16 * XS; i += NTHR) {
        xg[0][i] = (__bf16)0.f; xg[1][i] = (__bf16)0.f;
    }
    __syncthreads();                  // init barrier

    if (wave < 8) {
        // ===== layer-0: cols [16w,16w+16); x-side bf16 (time-batched), hidden i8 =====
        const int c = wave * 16 + ln16;
        const float bNi = -2.f * L2E * bih0[256 + c];
        const float bNh = -2.f * L2E * bhh0[256 + c];
        const float bR  = -L2E * (bih0[c] + bhh0[c]);
        const float bZ  = -L2E * (bih0[128 + c] + bhh0[128 + c]);
        bf16x8 wI[3][2];              // x-side, scale-folded
        i32x4  wH[3][2];              // hidden int8 K=64
        #pragma unroll
        for (int g = 0; g < 3; ++g) {
            const int row = g * 128 + c;
            const float sc = (g == 2) ? (-2.f * L2E) : (-L2E);
            #pragma unroll
            for (int q = 0; q < 2; ++q) {
                wI[g][q] = wfrag_bf(Wih0, 64, row, q * 32 + q8, sc);
                wH[g][q] = wfrag_i8(Whh0, 128, row, q * 64 + q16);
            }
        }

        // staging: 256 loaders (lanes 0..31 of each L0 wave)
        const bool loader = (lane < 32);
        const int lidx = wave * 32 + lane;
        const int sb = (lidx >> 6) & 3, scg = lidx & 63;
        const float* xp = x + (size_t)(brow + sb) * T_LEN * 64 + scg;
        float vx0 = 0.f, vx1 = 0.f, vx2 = 0.f;
        if (loader) {
            // prologue: x(0..3) -> xg[0] rows tq+4*sb; prefetch x(4..6)
            #pragma unroll
            for (int tq = 0; tq < 4; ++tq)
                xg[0][(tq + 4 * sb) * XS + scg] = (__bf16)xp[(size_t)tq * 64];
            vx0 = xp[4 * 64];
            vx1 = xp[5 * 64];
            vx2 = xp[6 * 64];
        }
        __syncthreads();              // publish xg[0]

        float hfv = 0.f;
        floatx4 pR, pZ, pNi;          // group x-side accs: acc[p] = step 4G+p
        for (int G = 0; G <= NG; ++G) {
            const bool act = (G < NG);
            #pragma unroll
            for (int p = 0; p < 4; ++p) {
                const int tt = 4 * G + p;
                __builtin_amdgcn_sched_barrier(0);
                BARRIER_LDS();        // the ONLY per-step barrier (lgkm only)
                // staging: write x(tt+4) into xg[(G+1)&1] row p+4*sb
                if (loader) {
                    if (tt + 4 < T_LEN)
                        xg[(G + 1) & 1][(p + 4 * sb) * XS + scg] = (__bf16)vx0;
                    vx0 = vx1; vx1 = vx2;
                    int tl = tt + 7; if (tl > T_LEN - 1) tl = T_LEN - 1;
                    vx2 = xp[(size_t)tl * 64];
                }
                if (act) {
                    if (p == 0) {     // group x-side GEMM: steps 4G..4G+3
                        bf16x8 ax0 = *(const bf16x8*)&xg[G & 1][ln16 * XS + q8];
                        bf16x8 ax1 = *(const bf16x8*)&xg[G & 1][ln16 * XS + 32 + q8];
                        floatx4 fR  = {bR, bR, bR, bR};
                        floatx4 fZ  = {bZ, bZ, bZ, bZ};
                        floatx4 fNi = {bNi, bNi, bNi, bNi};
                        __builtin_amdgcn_s_setprio(1);
                        fR  = MFMA_BF(ax0, wI[0][0], fR);  fR  = MFMA_BF(ax1, wI[0][1], fR);
                        fZ  = MFMA_BF(ax0, wI[1][0], fZ);  fZ  = MFMA_BF(ax1, wI[1][1], fZ);
                        fNi = MFMA_BF(ax0, wI[2][0], fNi); fNi = MFMA_BF(ax1, wI[2][1], fNi);
                        __builtin_amdgcn_s_setprio(0);
                        pR = fR; pZ = fZ; pNi = fNi;
                    }
                    // hidden side of step tt (sequential)
                    const int Rp = (tt + 1) & 1, Wc = tt & 1;
                    i32x4 ah[2];
                    #pragma unroll
                    for (int q = 0; q < 2; ++q)
                        ah[q] = *(const i32x4*)&h0b[Rp][ln16 * HIS + q * 64 + q16];
                    i32x4 cR = {0,0,0,0}, cZ = {0,0,0,0}, cNh = {0,0,0,0};
                    __builtin_amdgcn_s_setprio(1);
                    #pragma unroll
                    for (int q = 0; q < 2; ++q) {
                        cR  = MFMA_I8(ah[q], wH[0][q], cR);
                        cZ  = MFMA_I8(ah[q], wH[1][q], cZ);
                        cNh = MFMA_I8(ah[q], wH[2][q], cNh);
                    }
                    __builtin_amdgcn_s_setprio(0);
                    // gate math; x-side value for this step = acc reg p
                    const float pr  = fmaf((float)cR[0],  S_RZ, pR[p]);
                    const float pz  = fmaf((float)cZ[0],  S_RZ, pZ[p]);
                    const float phn = fmaf((float)cNh[0], S_N,  bNh);
                    const float r = rcpf(1.f + EXP2(pr));
                    const float z = rcpf(1.f + EXP2(pz));
                    const float n = 2.f * rcpf(1.f + EXP2(fmaf(r, phn, pNi[p]))) - 1.f;
                    const float h = n + z * (hfv - n);
                    hfv = h;
                    const signed char qv = (signed char)(int)__builtin_rintf(h * 127.f);
                    h0b[Wc][(quad * 4) * HIS + c] = qv;          // for L0 hidden (t+1)
                    h0g[G & 1][(p + 4 * quad) * HIS + c] = qv;   // group tile for L1
                }
            }
        }
    } else {
        // ===== layer-1 (group lag 4): cols [16wv,16wv+16); all int8 =====
        const int wv = wave - 8;
        const int c  = wv * 16 + ln16;
        const float bNi1 = -2.f * L2E * bih1[256 + c];
        const float bNh1 = -2.f * L2E * bhh1[256 + c];
        const float bR1  = -L2E * (bih1[c] + bhh1[c]);
        const float bZ1  = -L2E * (bih1[128 + c] + bhh1[128 + c]);
        i32x4 wI[3][2], wH[3][2];
        #pragma unroll
        for (int g = 0; g < 3; ++g) {
            const int row = g * 128 + c;
            #pragma unroll
            for (int q = 0; q < 2; ++q) {
                wI[g][q] = wfrag_i8(Wih1, 128, row, q * 64 + q16);
                wH[g][q] = wfrag_i8(Whh1, 128, row, q * 64 + q16);
            }
        }
        __syncthreads();              // match L0's xg-publish barrier

        float hfv = 0.f;
        i32x4 gR, gZ, gNi;            // group input-side accs: acc[p] = step 4(G-1)+p
        for (int G = 0; G <= NG; ++G) {
            const bool act = (G >= 1);
            #pragma unroll
            for (int p = 0; p < 4; ++p) {
                __builtin_amdgcn_sched_barrier(0);
                BARRIER_LDS();
                if (act) {
                    if (p == 0) {     // group input-side GEMM on h0(4(G-1)..4(G-1)+3)
                        i32x4 ag[2];
                        #pragma unroll
                        for (int q = 0; q < 2; ++q)
                            ag[q] = *(const i32x4*)&h0g[(G - 1) & 1][ln16 * HIS + q * 64 + q16];
                        i32x4 aR = {0,0,0,0}, aZ = {0,0,0,0}, aN = {0,0,0,0};
                        __builtin_amdgcn_s_setprio(1);
                        #pragma unroll
                        for (int q = 0; q < 2; ++q) {
                            aR = MFMA_I8(ag[q], wI[0][q], aR);
                            aZ = MFMA_I8(ag[q], wI[1][q], aZ);
                            aN = MFMA_I8(ag[q], wI[2][q], aN);
                        }
                        __builtin_amdgcn_s_setprio(0);
                        gR = aR; gZ = aZ; gNi = aN;
                    }
                    // hidden side of L1 step s = 4(G-1)+p (sequential)
                    const int s  = 4 * (G - 1) + p;
                    const int Rp = (s + 1) & 1, Wc = s & 1;
                    i32x4 a1[2];
                    #pragma unroll
                    for (int q = 0; q < 2; ++q)
                        a1[q] = *(const i32x4*)&h1b[Rp][ln16 * HIS + q * 64 + q16];
                    i32x4 cR = {0,0,0,0}, cZ = {0,0,0,0}, cNh = {0,0,0,0};
                    __builtin_amdgcn_s_setprio(1);
                    #pragma unroll
                    for (int q = 0; q < 2; ++q) {
                        cR  = MFMA_I8(a1[q], wH[0][q], cR);
                        cZ  = MFMA_I8(a1[q], wH[1][q], cZ);
                        cNh = MFMA_I8(a1[q], wH[2][q], cNh);
                    }
                    __builtin_amdgcn_s_setprio(0);
                    // gate math; input-side value = group acc reg p (exact i32 add)
                    const float pr  = fmaf((float)(cR[0] + gR[p]), S_RZ, bR1);
                    const float pz  = fmaf((float)(cZ[0] + gZ[p]), S_RZ, bZ1);
                    const float pin = fmaf((float)gNi[p], S_N, bNi1);
                    const float phn = fmaf((float)cNh[0], S_N, bNh1);
                    const float r = rcpf(1.f + EXP2(pr));
                    const float z = rcpf(1.f + EXP2(pz));
                    const float n = 2.f * rcpf(1.f + EXP2(fmaf(r, phn, pin))) - 1.f;
                    const float h = n + z * (hfv - n);
                    hfv = h;
                    h1b[Wc][(quad * 4) * HIS + c] =
                        (signed char)(int)__builtin_rintf(h * 127.f);
                }
            }
        }
        // publish final h1 (fp32 state) for the FC epilogue
        hfin[(quad * 4) * HFS + c] = hfv;
    }

    __syncthreads();
    // final FC: out[b] = h1(T-1)[b,:] . Wfc + bfc  (tile rows 0,4,8,12)
    {
        const int row = tid >> 5, l = tid & 31;
        if (row < 16 && (row & 3) == 0) {
            float s = 0.f;
            #pragma unroll
            for (int k = 0; k < 4; ++k)
                s += hfin[row * HFS + l + 32 * k] * Wfc[l + 32 * k];
            #pragma unroll
            for (int d = 16; d >= 1; d >>= 1) s += __shfl_down(s, d, 32);
            if (l == 0) out[brow + (row >> 2)] = s + bfc[0];
        }
    }
}

extern "C" void kernel_launch(void* const* d_in, const int* in_sizes, int n_in,
                              void* d_out, int out_size, void* d_ws, size_t ws_size,
                              hipStream_t stream) {
    const float* x    = (const float*)d_in[0];
    const float* Wih0 = (const float*)d_in[1];
    const float* Whh0 = (const float*)d_in[2];
    const float* bih0 = (const float*)d_in[3];
    const float* bhh0 = (const float*)d_in[4];
    const float* Wih1 = (const float*)d_in[5];
    const float* Whh1 = (const float*)d_in[6];
    const float* bih1 = (const float*)d_in[7];
    const float* bhh1 = (const float*)d_in[8];
    const float* Wfc  = (const float*)d_in[9];
    const float* bfc  = (const float*)d_in[10];
    float* out = (float*)d_out;

    hipLaunchKernelGGL(gru_fused, dim3(512 / BT), dim3(NTHR), 0, stream,
                       x, Wih0, Whh0, bih0, bhh0, Wih1, Whh1, bih1, bhh1, Wfc, bfc, out);
}